// Round 1
// baseline (293.860 us; speedup 1.0000x reference)
//
#include <hip/hip_runtime.h>
#include <hip/hip_bf16.h>
#include <math.h>

#define S_LEN 2048
#define NH    64        // B*H
#define TS    62        // d01/d02 outputs per tile (rows staged = 64)
#define NTILE 33        // ceil((S-2)/TS) with 33*62 == 2046 exactly

// ---------------------------------------------------------------------------
// Kernel 1: per (n, s-tile) compute content rows in registers, then pairwise
// distance norms d01[n][s] = ||c[s]-c[s+1]||, d02[n][s] = ||c[s]-c[s+2]||.
// ---------------------------------------------------------------------------
__global__ __launch_bounds__(256) void k_dist(const float* __restrict__ x,
                                              const float* __restrict__ W,
                                              float* __restrict__ d01,
                                              float* __restrict__ d02)
{
    __shared__ float As[64 * 128];   // 32 KB; x-tile, later overlaid with content tile
    const int tile = blockIdx.x;     // 0..32
    const int n    = blockIdx.y;     // 0..63
    const int bb   = n >> 4, hh = n & 15;
    const int s0   = tile * TS;
    const int t    = threadIdx.x;

    // stage x rows [s0, s0+64) for head (bb,hh): As[r*128 + d]
    #pragma unroll
    for (int i = 0; i < 8; i++) {
        int l  = t + 256 * i;            // 0..2047
        int r  = l >> 5;
        int d4 = (l & 31) << 2;
        int s  = s0 + r;
        float4 v = make_float4(0.f, 0.f, 0.f, 0.f);
        if (s < S_LEN)
            v = *(const float4*)&x[(((size_t)(bb * S_LEN + s) * 16 + hh)) * 128 + d4];
        *(float4*)&As[r * 128 + d4] = v;
    }
    __syncthreads();

    // microtile: thread computes rows rg..rg+7, cols e4..e4+3 of content
    const int e4 = (t & 31) << 2;
    const int rg = (t >> 5) << 3;
    float acc[8][4];
    #pragma unroll
    for (int rr = 0; rr < 8; rr++)
        #pragma unroll
        for (int c = 0; c < 4; c++) acc[rr][c] = 0.f;

    for (int k4 = 0; k4 < 128; k4 += 4) {
        float4 wr[4];
        #pragma unroll
        for (int c = 0; c < 4; c++)
            wr[c] = *(const float4*)&W[(e4 + c) * 128 + k4];   // W[e][k] row-major
        #pragma unroll
        for (int rr = 0; rr < 8; rr++) {
            float4 av = *(const float4*)&As[(rg + rr) * 128 + k4];  // wave-broadcast
            #pragma unroll
            for (int c = 0; c < 4; c++)
                acc[rr][c] += av.x * wr[c].x + av.y * wr[c].y +
                              av.z * wr[c].z + av.w * wr[c].w;
        }
    }
    __syncthreads();   // everyone done reading As before overlay

    // write content tile into the same LDS region
    #pragma unroll
    for (int rr = 0; rr < 8; rr++)
        *(float4*)&As[(rg + rr) * 128 + e4] =
            make_float4(acc[rr][0], acc[rr][1], acc[rr][2], acc[rr][3]);
    __syncthreads();

    // norms: items j=0..62 -> d01 (rows j, j+1), j=64..125 -> d02 (rows j-64, j-64+2)
    int j  = t >> 1;
    int h2 = t & 1;
    float part = 0.f;
    int r1 = 0, r2 = 0, sOut = 0;
    bool active = false;
    if (j < 64) {
        r1 = j; r2 = j + 1; sOut = s0 + j;
        active = (j <= TS) && (sOut < S_LEN - 1);
    } else {
        int jj = j - 64;
        r1 = jj; r2 = jj + 2; sOut = s0 + jj;
        active = (jj < TS) && (sOut < S_LEN - 2);
    }
    if (active) {
        #pragma unroll
        for (int e = 0; e < 64; e += 4) {
            float4 a  = *(const float4*)&As[r1 * 128 + h2 * 64 + e];
            float4 b4 = *(const float4*)&As[r2 * 128 + h2 * 64 + e];
            float dx = a.x - b4.x, dy = a.y - b4.y, dz = a.z - b4.z, dw = a.w - b4.w;
            part += dx * dx + dy * dy + dz * dz + dw * dw;
        }
    }
    part += __shfl_xor(part, 1);
    if (active && h2 == 0) {
        float dv = sqrtf(part);
        if (j < 64) d01[n * S_LEN + sOut] = dv;
        else        d02[n * S_LEN + sOut] = dv;
    }
}

// ---------------------------------------------------------------------------
// Kernel 2: between[b][s][h] = relu(1 - (path-direct)/max(direct,1e-6)) / (S-2)
// ---------------------------------------------------------------------------
__global__ __launch_bounds__(256) void k_between(const float* __restrict__ d01,
                                                 const float* __restrict__ d02,
                                                 float* __restrict__ bet)
{
    int tid = blockIdx.x * 256 + threadIdx.x;     // 0 .. 4*2048*16-1
    if (tid >= 4 * S_LEN * 16) return;
    int h = tid & 15;
    int s = (tid >> 4) & (S_LEN - 1);
    int b = tid >> 15;
    float v = 0.f;
    if (s >= 1 && s <= S_LEN - 2) {
        int n = b * 16 + h;
        int i = s - 1;
        float p  = d01[n * S_LEN + i] + d01[n * S_LEN + i + 1];
        float dd = d02[n * S_LEN + i];
        float sc = 1.f - (p - dd) / fmaxf(dd, 1e-6f);
        v = fmaxf(sc, 0.f) * (1.f / (float)(S_LEN - 2));
    }
    bet[tid] = v;
}

// ---------------------------------------------------------------------------
// Kernel 3: rope tables fcos/fsin[s][j], j = 0..63
// ---------------------------------------------------------------------------
__global__ __launch_bounds__(256) void k_tables(float* __restrict__ fcos,
                                                float* __restrict__ fsin)
{
    int tid = blockIdx.x * 256 + threadIdx.x;     // 0 .. 2048*64-1
    int j = tid & 63;
    int s = tid >> 6;
    float base = powf(10000.f, -(float)(2 * j) * (1.f / 128.f));
    float fr = (float)s * base;
    fcos[tid] = cosf(fr);
    fsin[tid] = sinf(fr);
}

// ---------------------------------------------------------------------------
// Kernel 4: RoPE with interpolated adjusted positions. One thread per pair.
// ---------------------------------------------------------------------------
__global__ __launch_bounds__(256) void k_rope(const float* __restrict__ x,
                                              const float* __restrict__ bet,
                                              const float* __restrict__ fcos,
                                              const float* __restrict__ fsin,
                                              float* __restrict__ out)
{
    int tid = blockIdx.x * 256 + threadIdx.x;     // pair index, 8388608 total
    int j = tid & 63;
    int s = (tid >> 10) & (S_LEN - 1);

    float between = bet[tid >> 6];                // [b][s][h] layout, wave-uniform
    float adj = (float)s + (between - 0.5f) * 0.1f;
    adj = fminf(fmaxf(adj, 0.f), (float)(S_LEN - 1));
    float lo = floorf(adj), hi = ceilf(adj);
    float frac = adj - lo;
    int li = (int)lo, hii = (int)hi;

    float cl = fcos[li * 64 + j],  ch = fcos[hii * 64 + j];
    float sl = fsin[li * 64 + j],  sh = fsin[hii * 64 + j];
    float ci = (1.f - frac) * cl + frac * ch;
    float si = (1.f - frac) * sl + frac * sh;

    float2 xv = ((const float2*)x)[tid];
    float oe = xv.x * ci - xv.y * si;
    float oo = xv.y * ci + xv.x * si;
    ((float2*)out)[tid] = make_float2(oe, oo);
}

// ---------------------------------------------------------------------------
extern "C" void kernel_launch(void* const* d_in, const int* in_sizes, int n_in,
                              void* d_out, int out_size, void* d_ws, size_t ws_size,
                              hipStream_t stream)
{
    const float* x = (const float*)d_in[0];
    const float* W = (const float*)d_in[1];
    // d_in[2] (bias b) cancels in d01/d02 differences -> unused
    float* out = (float*)d_out;

    float* ws   = (float*)d_ws;
    float* d01  = ws;                 // 64*2048
    float* d02  = ws + 131072;        // 64*2048
    float* bet  = ws + 262144;        // 4*2048*16
    float* fcos = ws + 393216;        // 2048*64
    float* fsin = ws + 524288;        // 2048*64

    k_dist   <<<dim3(NTILE, NH), 256, 0, stream>>>(x, W, d01, d02);
    k_tables <<<512,  256, 0, stream>>>(fcos, fsin);
    k_between<<<512,  256, 0, stream>>>(d01, d02, bet);
    k_rope   <<<32768, 256, 0, stream>>>(x, bet, fcos, fsin, out);
}

// Round 2
// 145.132 us; speedup vs baseline: 2.0248x; 2.0248x over previous
//
#include <hip/hip_runtime.h>
#include <hip/hip_bf16.h>
#include <math.h>

#define S_LEN 2048
#define NH    64        // B*H
#define TS    62        // d01/d02 outputs per tile (rows staged = 64)
#define NTILE 33        // 33*62 == 2046 == S-2 exactly

typedef __attribute__((ext_vector_type(8))) short short8;
typedef __attribute__((ext_vector_type(4))) float f32x4;

__device__ __forceinline__ unsigned short f2bf(float f) {
    unsigned int u = __float_as_uint(f);
    return (unsigned short)((u + 0x7FFFu + ((u >> 16) & 1u)) >> 16);   // RNE
}

// ---------------------------------------------------------------------------
// k_misc: blocks 0..511 build rope tables; blocks 512..575 convert W -> bf16.
// ---------------------------------------------------------------------------
__global__ __launch_bounds__(256) void k_misc(const float* __restrict__ W,
                                              unsigned short* __restrict__ Wbf,
                                              float* __restrict__ fcos,
                                              float* __restrict__ fsin)
{
    int bid = blockIdx.x;
    if (bid < 512) {
        int tid = bid * 256 + threadIdx.x;        // 0 .. 2048*64-1
        int j = tid & 63;
        int s = tid >> 6;
        float base = powf(10000.f, -(float)(2 * j) * (1.f / 128.f));
        float fr = (float)s * base;
        fcos[tid] = cosf(fr);
        fsin[tid] = sinf(fr);
    } else {
        int idx = (bid - 512) * 256 + threadIdx.x;  // 0 .. 16383
        Wbf[idx] = f2bf(W[idx]);
    }
}

// ---------------------------------------------------------------------------
// k_dist: per (n, s-tile): content = x_tile * W^T via bf16 MFMA, then
// d01[n][s]=||c[s]-c[s+1]||, d02[n][s]=||c[s]-c[s+2]||.
// LDS: Xs 64x(128+8)bf16, Wsh 128x(128+8)bf16; Cs (transposed content,
// 128 cols x stride 65 fp32) overlays them after the MFMA phase.
// ---------------------------------------------------------------------------
__global__ __launch_bounds__(256) void k_dist(const float* __restrict__ x,
                                              const unsigned short* __restrict__ Wbf,
                                              float* __restrict__ d01,
                                              float* __restrict__ d02)
{
    __shared__ char smem[52224];
    unsigned short* Xs  = (unsigned short*)smem;            // stride 136 bf16
    unsigned short* Wsh = (unsigned short*)(smem + 17408);  // stride 136 bf16
    float*          Cs  = (float*)smem;                     // 128 x 65 fp32 overlay

    const int tile = blockIdx.x;     // 0..32
    const int n    = blockIdx.y;     // 0..63
    const int bb   = n >> 4, hh = n & 15;
    const int s0   = tile * TS;
    const int t    = threadIdx.x;
    const int w    = t >> 6;         // wave 0..3
    const int l    = t & 63;
    const int m    = l & 15;
    const int q    = l >> 4;

    // ---- stage x tile (64 rows x 128 cols fp32 -> bf16), coalesced float4 ----
    #pragma unroll
    for (int i = 0; i < 8; i++) {
        int idx = t + 256 * i;               // 0..2047
        int r   = idx >> 5;                  // row 0..63  (s0+r <= 2047 always)
        int c4  = idx & 31;                  // float4 index
        float4 v = *(const float4*)&x[(((size_t)(bb * S_LEN + s0 + r) * 16 + hh)) * 128 + c4 * 4];
        ushort4 p;
        p.x = f2bf(v.x); p.y = f2bf(v.y); p.z = f2bf(v.z); p.w = f2bf(v.w);
        *(ushort4*)&Xs[r * 136 + c4 * 4] = p;
    }
    // ---- stage W (pre-converted bf16, 128x128), 16B chunks ----
    #pragma unroll
    for (int i = 0; i < 8; i++) {
        int idx = t + 256 * i;               // 0..2047
        int r   = idx >> 4;                  // row 0..127
        int c8  = idx & 15;                  // 8-bf16 chunk
        uint4 v = *(const uint4*)&Wbf[r * 128 + c8 * 8];
        *(uint4*)&Wsh[r * 136 + c8 * 8] = v;
    }
    __syncthreads();

    // ---- MFMA: wave w -> output rows 16w..16w+15, all 8 col-tiles ----
    f32x4 acc[8];
    #pragma unroll
    for (int ct = 0; ct < 8; ct++) acc[ct] = (f32x4){0.f, 0.f, 0.f, 0.f};

    #pragma unroll
    for (int kk = 0; kk < 4; kk++) {
        short8 a = *(const short8*)&Xs[(16 * w + m) * 136 + kk * 32 + q * 8];
        #pragma unroll
        for (int ct = 0; ct < 8; ct++) {
            short8 b = *(const short8*)&Wsh[(16 * ct + m) * 136 + kk * 32 + q * 8];
            acc[ct] = __builtin_amdgcn_mfma_f32_16x16x32_bf16(a, b, acc[ct], 0, 0, 0);
        }
    }
    __syncthreads();   // all frag reads done before overlaying Cs

    // ---- write content transposed: Cs[col*65 + row] ----
    #pragma unroll
    for (int ct = 0; ct < 8; ct++) {
        int col   = 16 * ct + m;
        int rbase = 16 * w + q * 4;
        #pragma unroll
        for (int r = 0; r < 4; r++)
            Cs[col * 65 + rbase + r] = acc[ct][r];
    }
    __syncthreads();

    // ---- norms: wave {0,1} -> d01 (j in [0,62]), wave {2,3} -> d02 (j in [0,61])
    // lane pair (g=l&1) splits the 128-col sum; reads are consecutive-lane, conflict-free
    int which = w >> 1;                  // 0: d01, 1: d02
    int j     = (w & 1) * 32 + (l >> 1);
    int g     = l & 1;
    int lim   = which ? (TS - 1) : TS;
    bool active = (j <= lim);
    float part = 0.f;
    if (active) {
        int r1 = j, r2 = j + 1 + which;
        #pragma unroll 8
        for (int i = 0; i < 64; i++) {
            int e = g + 2 * i;
            float d = Cs[e * 65 + r1] - Cs[e * 65 + r2];
            part += d * d;
        }
    }
    part += __shfl_xor(part, 1);
    if (active && g == 0) {
        float dv = sqrtf(part);
        if (which == 0) d01[n * S_LEN + s0 + j] = dv;   // boundary dupes are bitwise-equal
        else            d02[n * S_LEN + s0 + j] = dv;
    }
}

// ---------------------------------------------------------------------------
// k_between: between[b][s][h] = relu(1-(path-direct)/max(direct,1e-6))/(S-2)
// ---------------------------------------------------------------------------
__global__ __launch_bounds__(256) void k_between(const float* __restrict__ d01,
                                                 const float* __restrict__ d02,
                                                 float* __restrict__ bet)
{
    int tid = blockIdx.x * 256 + threadIdx.x;     // 0 .. 4*2048*16-1
    if (tid >= 4 * S_LEN * 16) return;
    int h = tid & 15;
    int s = (tid >> 4) & (S_LEN - 1);
    int b = tid >> 15;
    float v = 0.f;
    if (s >= 1 && s <= S_LEN - 2) {
        int nn = b * 16 + h;
        int i = s - 1;
        float p  = d01[nn * S_LEN + i] + d01[nn * S_LEN + i + 1];
        float dd = d02[nn * S_LEN + i];
        float sc = 1.f - (p - dd) / fmaxf(dd, 1e-6f);
        v = fmaxf(sc, 0.f) * (1.f / (float)(S_LEN - 2));
    }
    bet[tid] = v;
}

// ---------------------------------------------------------------------------
// k_rope: one thread per (even,odd) pair; float2 in/out, tables from L2.
// ---------------------------------------------------------------------------
__global__ __launch_bounds__(256) void k_rope(const float* __restrict__ x,
                                              const float* __restrict__ bet,
                                              const float* __restrict__ fcos,
                                              const float* __restrict__ fsin,
                                              float* __restrict__ out)
{
    int tid = blockIdx.x * 256 + threadIdx.x;     // pair index, 8388608 total
    int j = tid & 63;
    int s = (tid >> 10) & (S_LEN - 1);

    float between = bet[tid >> 6];                // [b][s][h], wave-uniform
    float adj = (float)s + (between - 0.5f) * 0.1f;
    adj = fminf(fmaxf(adj, 0.f), (float)(S_LEN - 1));
    float lo = floorf(adj), hi = ceilf(adj);
    float frac = adj - lo;
    int li = (int)lo, hii = (int)hi;

    float cl = fcos[li * 64 + j],  ch = fcos[hii * 64 + j];
    float sl = fsin[li * 64 + j],  sh = fsin[hii * 64 + j];
    float ci = (1.f - frac) * cl + frac * ch;
    float si = (1.f - frac) * sl + frac * sh;

    float2 xv = ((const float2*)x)[tid];
    float oe = xv.x * ci - xv.y * si;
    float oo = xv.y * ci + xv.x * si;
    ((float2*)out)[tid] = make_float2(oe, oo);
}

// ---------------------------------------------------------------------------
extern "C" void kernel_launch(void* const* d_in, const int* in_sizes, int n_in,
                              void* d_out, int out_size, void* d_ws, size_t ws_size,
                              hipStream_t stream)
{
    const float* x = (const float*)d_in[0];
    const float* W = (const float*)d_in[1];
    // d_in[2] (bias) cancels in the d01/d02 differences -> unused
    float* out = (float*)d_out;

    float* ws   = (float*)d_ws;
    float* d01  = ws;                                   // 64*2048
    float* d02  = ws + 131072;                          // 64*2048
    float* bet  = ws + 262144;                          // 4*2048*16
    float* fcos = ws + 393216;                          // 2048*64
    float* fsin = ws + 524288;                          // 2048*64
    unsigned short* Wbf = (unsigned short*)(ws + 655360); // 128*128 bf16

    k_misc   <<<576, 256, 0, stream>>>(W, Wbf, fcos, fsin);
    k_dist   <<<dim3(NTILE, NH), 256, 0, stream>>>(x, Wbf, d01, d02);
    k_between<<<512,  256, 0, stream>>>(d01, d02, bet);
    k_rope   <<<32768, 256, 0, stream>>>(x, bet, fcos, fsin, out);
}

// Round 5
// 137.068 us; speedup vs baseline: 2.1439x; 1.0588x over previous
//
#include <hip/hip_runtime.h>
#include <hip/hip_bf16.h>
#include <math.h>

#define S_LEN 2048
#define NH    64        // B*H
#define TS    62        // d01/d02 outputs per tile (rows staged = 64)
#define NTILE 33        // 33*62 == 2046 == S-2 exactly

typedef __attribute__((ext_vector_type(8))) short short8;
typedef __attribute__((ext_vector_type(4))) float f32x4;

__device__ __forceinline__ unsigned short f2bf(float f) {
    unsigned int u = __float_as_uint(f);
    return (unsigned short)((u + 0x7FFFu + ((u >> 16) & 1u)) >> 16);   // RNE
}

// ---------------------------------------------------------------------------
// k_misc: blocks 0..511 build interleaved (cos,sin) table; 512..575 W -> bf16.
// (eager-proven in R3; tab consumed with float4 reads in k_rope4)
// ---------------------------------------------------------------------------
__global__ __launch_bounds__(256) void k_misc(const float* __restrict__ W,
                                              unsigned short* __restrict__ Wbf,
                                              float2* __restrict__ tab)
{
    int bid = blockIdx.x;
    if (bid < 512) {
        int tid = bid * 256 + threadIdx.x;        // 0 .. 2048*64-1
        int j = tid & 63;
        int s = tid >> 6;
        float base = powf(10000.f, -(float)(2 * j) * (1.f / 128.f));
        float fr = (float)s * base;
        tab[tid] = make_float2(cosf(fr), sinf(fr));
    } else {
        int idx = (bid - 512) * 256 + threadIdx.x;  // 0 .. 16383
        Wbf[idx] = f2bf(W[idx]);
    }
}

// ---------------------------------------------------------------------------
// k_dist: VERBATIM from round 2 (passed eager + replay). Per (n, s-tile):
// content = x_tile * W^T via bf16 MFMA, then d01/d02 norms -> global.
// ---------------------------------------------------------------------------
__global__ __launch_bounds__(256) void k_dist(const float* __restrict__ x,
                                              const unsigned short* __restrict__ Wbf,
                                              float* __restrict__ d01,
                                              float* __restrict__ d02)
{
    __shared__ char smem[52224];
    unsigned short* Xs  = (unsigned short*)smem;            // stride 136 bf16
    unsigned short* Wsh = (unsigned short*)(smem + 17408);  // stride 136 bf16
    float*          Cs  = (float*)smem;                     // 128 x 65 fp32 overlay

    const int tile = blockIdx.x;     // 0..32
    const int n    = blockIdx.y;     // 0..63
    const int bb   = n >> 4, hh = n & 15;
    const int s0   = tile * TS;
    const int t    = threadIdx.x;
    const int w    = t >> 6;         // wave 0..3
    const int l    = t & 63;
    const int m    = l & 15;
    const int q    = l >> 4;

    // ---- stage x tile (64 rows x 128 cols fp32 -> bf16), coalesced float4 ----
    #pragma unroll
    for (int i = 0; i < 8; i++) {
        int idx = t + 256 * i;               // 0..2047
        int r   = idx >> 5;                  // row 0..63  (s0+r <= 2047 always)
        int c4  = idx & 31;                  // float4 index
        float4 v = *(const float4*)&x[(((size_t)(bb * S_LEN + s0 + r) * 16 + hh)) * 128 + c4 * 4];
        ushort4 p;
        p.x = f2bf(v.x); p.y = f2bf(v.y); p.z = f2bf(v.z); p.w = f2bf(v.w);
        *(ushort4*)&Xs[r * 136 + c4 * 4] = p;
    }
    // ---- stage W (pre-converted bf16, 128x128), 16B chunks ----
    #pragma unroll
    for (int i = 0; i < 8; i++) {
        int idx = t + 256 * i;               // 0..2047
        int r   = idx >> 4;                  // row 0..127
        int c8  = idx & 15;                  // 8-bf16 chunk
        uint4 v = *(const uint4*)&Wbf[r * 128 + c8 * 8];
        *(uint4*)&Wsh[r * 136 + c8 * 8] = v;
    }
    __syncthreads();

    // ---- MFMA: wave w -> output rows 16w..16w+15, all 8 col-tiles ----
    f32x4 acc[8];
    #pragma unroll
    for (int ct = 0; ct < 8; ct++) acc[ct] = (f32x4){0.f, 0.f, 0.f, 0.f};

    #pragma unroll
    for (int kk = 0; kk < 4; kk++) {
        short8 a = *(const short8*)&Xs[(16 * w + m) * 136 + kk * 32 + q * 8];
        #pragma unroll
        for (int ct = 0; ct < 8; ct++) {
            short8 b = *(const short8*)&Wsh[(16 * ct + m) * 136 + kk * 32 + q * 8];
            acc[ct] = __builtin_amdgcn_mfma_f32_16x16x32_bf16(a, b, acc[ct], 0, 0, 0);
        }
    }
    __syncthreads();   // all frag reads done before overlaying Cs

    // ---- write content transposed: Cs[col*65 + row] ----
    #pragma unroll
    for (int ct = 0; ct < 8; ct++) {
        int col   = 16 * ct + m;
        int rbase = 16 * w + q * 4;
        #pragma unroll
        for (int r = 0; r < 4; r++)
            Cs[col * 65 + rbase + r] = acc[ct][r];
    }
    __syncthreads();

    // ---- norms: wave {0,1} -> d01 (j in [0,62]), wave {2,3} -> d02 (j in [0,61])
    int which = w >> 1;                  // 0: d01, 1: d02
    int j     = (w & 1) * 32 + (l >> 1);
    int g     = l & 1;
    int lim   = which ? (TS - 1) : TS;
    bool active = (j <= lim);
    float part = 0.f;
    if (active) {
        int r1 = j, r2 = j + 1 + which;
        #pragma unroll 8
        for (int i = 0; i < 64; i++) {
            int e = g + 2 * i;
            float d = Cs[e * 65 + r1] - Cs[e * 65 + r2];
            part += d * d;
        }
    }
    part += __shfl_xor(part, 1);
    if (active && g == 0) {
        float dv = sqrtf(part);
        if (which == 0) d01[n * S_LEN + s0 + j] = dv;   // boundary dupes are bitwise-equal
        else            d02[n * S_LEN + s0 + j] = dv;
    }
}

// ---------------------------------------------------------------------------
// k_rope4: pure elementwise — one thread per float4 (2 rope pairs).
// between computed inline from global d01/d02 (k_between's proven formula).
// No LDS, no barriers -> no races possible.
// ---------------------------------------------------------------------------
__global__ __launch_bounds__(256) void k_rope4(const float* __restrict__ x,
                                               const float* __restrict__ d01,
                                               const float* __restrict__ d02,
                                               const float2* __restrict__ tab,
                                               float* __restrict__ out)
{
    int tid4 = blockIdx.x * 256 + threadIdx.x;   // float4 index, 0 .. 4194303
    int d4   = tid4 & 31;                        // float4 within the 128-float row
    int rem  = tid4 >> 5;                        // [b][s][h] row id
    int h    = rem & 15;
    int s    = (rem >> 4) & (S_LEN - 1);
    int b    = rem >> 15;
    int n    = b * 16 + h;

    // between (0 at s=0 and s=S-1), proven k_between math inlined
    float bet = 0.f;
    if (s >= 1 && s <= S_LEN - 2) {
        int i = s - 1;
        float p  = d01[n * S_LEN + i] + d01[n * S_LEN + i + 1];
        float dd = d02[n * S_LEN + i];
        float sc = 1.f - (p - dd) / fmaxf(dd, 1e-6f);
        bet = fmaxf(sc, 0.f) * (1.f / (float)(S_LEN - 2));
    }

    float adj = (float)s + (bet - 0.5f) * 0.1f;
    adj = fminf(fmaxf(adj, 0.f), (float)(S_LEN - 1));
    float lof = floorf(adj), hif = ceilf(adj);
    float frac = adj - lof;
    int lo = (int)lof, hi = (int)hif;

    // pairs j0 = 2*d4, j1 = 2*d4+1; tab is (cos,sin) interleaved per (s,j)
    float4 tl = *(const float4*)&tab[lo * 64 + 2 * d4];
    float4 th = *(const float4*)&tab[hi * 64 + 2 * d4];
    float ci0 = (1.f - frac) * tl.x + frac * th.x;
    float si0 = (1.f - frac) * tl.y + frac * th.y;
    float ci1 = (1.f - frac) * tl.z + frac * th.z;
    float si1 = (1.f - frac) * tl.w + frac * th.w;

    float4 xv = ((const float4*)x)[tid4];
    float4 o;
    o.x = xv.x * ci0 - xv.y * si0;
    o.y = xv.y * ci0 + xv.x * si0;
    o.z = xv.z * ci1 - xv.w * si1;
    o.w = xv.w * ci1 + xv.z * si1;
    ((float4*)out)[tid4] = o;
}

// ---------------------------------------------------------------------------
extern "C" void kernel_launch(void* const* d_in, const int* in_sizes, int n_in,
                              void* d_out, int out_size, void* d_ws, size_t ws_size,
                              hipStream_t stream)
{
    const float* x = (const float*)d_in[0];
    const float* W = (const float*)d_in[1];
    // d_in[2] (bias) cancels in the d01/d02 differences -> unused
    float* out = (float*)d_out;

    float* ws = (float*)d_ws;
    float* d01 = ws;                                      // 64*2048
    float* d02 = ws + 131072;                             // 64*2048
    float2* tab = (float2*)(ws + 262144);                 // 2048*64 float2 = 1 MB
    unsigned short* Wbf = (unsigned short*)(ws + 524288); // 128*128 bf16

    k_misc <<<576, 256, 0, stream>>>(W, Wbf, tab);
    k_dist <<<dim3(NTILE, NH), 256, 0, stream>>>(x, Wbf, d01, d02);
    k_rope4<<<16384, 256, 0, stream>>>(x, d01, d02, tab, out);
}

// Round 6
// 136.198 us; speedup vs baseline: 2.1576x; 1.0064x over previous
//
#include <hip/hip_runtime.h>
#include <hip/hip_bf16.h>
#include <math.h>

#define S_LEN 2048
#define NH    64        // B*H
#define TS    62        // d01/d02 outputs per tile (rows staged = 64)
#define NTILE 33        // 33*62 == 2046 == S-2 exactly
#define NDIST (NTILE * NH)   // 2112 dist blocks

typedef __attribute__((ext_vector_type(8))) short short8;
typedef __attribute__((ext_vector_type(4))) float f32x4;

__device__ __forceinline__ unsigned short f2bf(float f) {
    unsigned int u = __float_as_uint(f);
    return (unsigned short)((u + 0x7FFFu + ((u >> 16) & 1u)) >> 16);   // RNE
}

// ---------------------------------------------------------------------------
// k_dm: blocks 0..2111 -> dist work (R5's proven k_dist, W staged from fp32);
//       blocks 2112..2623 -> rope (cos,sin) table.
// ---------------------------------------------------------------------------
__global__ __launch_bounds__(256) void k_dm(const float* __restrict__ x,
                                            const float* __restrict__ W,
                                            float* __restrict__ d01,
                                            float* __restrict__ d02,
                                            float2* __restrict__ tab)
{
    __shared__ char smem[52224];
    unsigned short* Xs  = (unsigned short*)smem;            // 64 x 136 bf16
    unsigned short* Wsh = (unsigned short*)(smem + 17408);  // 128 x 136 bf16
    float*          Cs  = (float*)smem;                     // 128 x 68 fp32 overlay

    const int bid = blockIdx.x;
    const int t   = threadIdx.x;

    if (bid >= NDIST) {
        // ---- tab blocks: 512 blocks x 256 threads -> 131072 (cos,sin) ----
        int tid = (bid - NDIST) * 256 + t;        // 0 .. 2048*64-1
        int j = tid & 63;
        int s = tid >> 6;
        float base = powf(10000.f, -(float)(2 * j) * (1.f / 128.f));
        float fr = (float)s * base;
        tab[tid] = make_float2(cosf(fr), sinf(fr));
        return;
    }

    const int tile = bid >> 6;       // 0..32
    const int n    = bid & 63;       // 0..63
    const int bb   = n >> 4, hh = n & 15;
    const int s0   = tile * TS;
    const int w    = t >> 6;         // wave 0..3
    const int l    = t & 63;
    const int m    = l & 15;
    const int q    = l >> 4;

    // ---- stage x tile (64 rows x 128 cols fp32 -> bf16), coalesced float4 ----
    #pragma unroll
    for (int i = 0; i < 8; i++) {
        int idx = t + 256 * i;               // 0..2047
        int r   = idx >> 5;                  // row 0..63  (s0+r <= 2047 always)
        int c4  = idx & 31;                  // float4 index
        float4 v = *(const float4*)&x[(((size_t)(bb * S_LEN + s0 + r) * 16 + hh)) * 128 + c4 * 4];
        ushort4 p;
        p.x = f2bf(v.x); p.y = f2bf(v.y); p.z = f2bf(v.z); p.w = f2bf(v.w);
        *(ushort4*)&Xs[r * 136 + c4 * 4] = p;
    }
    // ---- stage W (fp32 -> bf16, 128x128; W is L2-resident) ----
    #pragma unroll
    for (int i = 0; i < 8; i++) {
        int idx = t + 256 * i;               // 0..2047
        int r   = idx >> 4;                  // row 0..127
        int c8  = idx & 15;                  // 8-float chunk
        float4 a = *(const float4*)&W[r * 128 + c8 * 8];
        float4 b = *(const float4*)&W[r * 128 + c8 * 8 + 4];
        ushort4 p0, p1;
        p0.x = f2bf(a.x); p0.y = f2bf(a.y); p0.z = f2bf(a.z); p0.w = f2bf(a.w);
        p1.x = f2bf(b.x); p1.y = f2bf(b.y); p1.z = f2bf(b.z); p1.w = f2bf(b.w);
        *(ushort4*)&Wsh[r * 136 + c8 * 8]     = p0;
        *(ushort4*)&Wsh[r * 136 + c8 * 8 + 4] = p1;
    }
    __syncthreads();

    // ---- MFMA: wave w -> output rows 16w..16w+15, all 8 col-tiles ----
    f32x4 acc[8];
    #pragma unroll
    for (int ct = 0; ct < 8; ct++) acc[ct] = (f32x4){0.f, 0.f, 0.f, 0.f};

    #pragma unroll
    for (int kk = 0; kk < 4; kk++) {
        short8 a = *(const short8*)&Xs[(16 * w + m) * 136 + kk * 32 + q * 8];
        #pragma unroll
        for (int ct = 0; ct < 8; ct++) {
            short8 b = *(const short8*)&Wsh[(16 * ct + m) * 136 + kk * 32 + q * 8];
            acc[ct] = __builtin_amdgcn_mfma_f32_16x16x32_bf16(a, b, acc[ct], 0, 0, 0);
        }
    }
    __syncthreads();   // all frag reads done before overlaying Cs

    // ---- write content transposed: Cs[col*68 + row], 16B-aligned b128 writes ----
    #pragma unroll
    for (int ct = 0; ct < 8; ct++) {
        int col   = 16 * ct + m;
        int rbase = 16 * w + q * 4;
        *(f32x4*)&Cs[col * 68 + rbase] = acc[ct];
    }
    __syncthreads();

    // ---- norms: waves {0,1} -> d01 (j 0..62), waves {2,3} -> d02 (j 0..61) ----
    int which = w >> 1;                  // 0: d01, 1: d02
    int j     = (w & 1) * 32 + (l >> 1);
    int g     = l & 1;
    int lim   = which ? (TS - 1) : TS;
    bool active = (j <= lim);
    float part = 0.f;
    if (active) {
        int r1 = j, r2 = j + 1 + which;
        #pragma unroll 8
        for (int i = 0; i < 64; i++) {
            int e = g + 2 * i;
            float d = Cs[e * 68 + r1] - Cs[e * 68 + r2];
            part += d * d;
        }
    }
    part += __shfl_xor(part, 1);
    if (active && g == 0) {
        float dv = sqrtf(part);
        if (which == 0) d01[n * S_LEN + s0 + j] = dv;   // boundary dupes are bitwise-equal
        else            d02[n * S_LEN + s0 + j] = dv;
    }
}

// ---------------------------------------------------------------------------
// k_rope4: pure elementwise — one thread per float4 (2 rope pairs).
// between computed inline from global d01/d02. No LDS, no barriers.
// ---------------------------------------------------------------------------
__global__ __launch_bounds__(256) void k_rope4(const float* __restrict__ x,
                                               const float* __restrict__ d01,
                                               const float* __restrict__ d02,
                                               const float2* __restrict__ tab,
                                               float* __restrict__ out)
{
    int tid4 = blockIdx.x * 256 + threadIdx.x;   // float4 index, 0 .. 4194303
    int d4   = tid4 & 31;                        // float4 within the 128-float row
    int rem  = tid4 >> 5;                        // [b][s][h] row id
    int h    = rem & 15;
    int s    = (rem >> 4) & (S_LEN - 1);
    int b    = rem >> 15;
    int n    = b * 16 + h;

    // between (0 at s=0 and s=S-1)
    float bet = 0.f;
    if (s >= 1 && s <= S_LEN - 2) {
        int i = s - 1;
        float p  = d01[n * S_LEN + i] + d01[n * S_LEN + i + 1];
        float dd = d02[n * S_LEN + i];
        float sc = 1.f - (p - dd) / fmaxf(dd, 1e-6f);
        bet = fmaxf(sc, 0.f) * (1.f / (float)(S_LEN - 2));
    }

    float adj = (float)s + (bet - 0.5f) * 0.1f;
    adj = fminf(fmaxf(adj, 0.f), (float)(S_LEN - 1));
    float lof = floorf(adj), hif = ceilf(adj);
    float frac = adj - lof;
    int lo = (int)lof, hi = (int)hif;

    // pairs j0 = 2*d4, j1 = 2*d4+1; tab is (cos,sin) interleaved per (s,j)
    float4 tl = *(const float4*)&tab[lo * 64 + 2 * d4];
    float4 th = *(const float4*)&tab[hi * 64 + 2 * d4];
    float ci0 = (1.f - frac) * tl.x + frac * th.x;
    float si0 = (1.f - frac) * tl.y + frac * th.y;
    float ci1 = (1.f - frac) * tl.z + frac * th.z;
    float si1 = (1.f - frac) * tl.w + frac * th.w;

    float4 xv = ((const float4*)x)[tid4];
    float4 o;
    o.x = xv.x * ci0 - xv.y * si0;
    o.y = xv.y * ci0 + xv.x * si0;
    o.z = xv.z * ci1 - xv.w * si1;
    o.w = xv.w * ci1 + xv.z * si1;
    ((float4*)out)[tid4] = o;
}

// ---------------------------------------------------------------------------
extern "C" void kernel_launch(void* const* d_in, const int* in_sizes, int n_in,
                              void* d_out, int out_size, void* d_ws, size_t ws_size,
                              hipStream_t stream)
{
    const float* x = (const float*)d_in[0];
    const float* W = (const float*)d_in[1];
    // d_in[2] (bias) cancels in the d01/d02 differences -> unused
    float* out = (float*)d_out;

    float* ws = (float*)d_ws;
    float* d01 = ws;                                      // 64*2048
    float* d02 = ws + 131072;                             // 64*2048
    float2* tab = (float2*)(ws + 262144);                 // 2048*64 float2 = 1 MB

    k_dm   <<<NDIST + 512, 256, 0, stream>>>(x, W, d01, d02, tab);
    k_rope4<<<16384, 256, 0, stream>>>(x, d01, d02, tab, out);
}